// Round 1
// baseline (431.273 us; speedup 1.0000x reference)
//
#include <hip/hip_runtime.h>
#include <hip/hip_bf16.h>

// Problem constants
#define D_M   512
#define H_M   1024
#define G_N   8
#define E_N   8
#define T_N   1024
#define NEXP  64
#define CAP   1024

#define LDK   520          // padded K row stride for xl (bf16 elems): 520*2=1040 B, 16B-aligned

typedef __attribute__((ext_vector_type(8))) short bf16x8;
typedef __attribute__((ext_vector_type(4))) float f32x4;
typedef __attribute__((ext_vector_type(4))) unsigned int u32x4;

// single-instruction packed f32->bf16 (RNE), replaces ~10-op manual pack
__device__ __forceinline__ unsigned pack2(float a, float b) {
  unsigned r;
  asm("v_cvt_pk_bf16_f32 %0, %1, %2" : "=v"(r) : "v"(a), "v"(b));
  return r;
}
__device__ __forceinline__ unsigned short f2bf(float f) {
  unsigned u = __builtin_bit_cast(unsigned, f);
  u = (u + 0x7fffu + ((u >> 16) & 1u)) >> 16;   // RTN-even
  return (unsigned short)u;
}

// ---------------- routing (fp32, exact) + expert-list build (merged) ----------------
__global__ __launch_bounds__(64) void k_route(
    const float* __restrict__ x, const float* __restrict__ g1,
    const float* __restrict__ g2, float* __restrict__ slotW,
    int* __restrict__ counts, int* __restrict__ list) {
  __shared__ float xs[D_M];
  __shared__ float l2s[G_N][E_N];
  __shared__ float l1s[G_N];
  __shared__ float l1part[G_N][8];
  const int t = blockIdx.x;
  const int lane = threadIdx.x;
  const float* xr = x + (size_t)t * D_M;
  for (int i = lane; i < D_M; i += 64) xs[i] = xr[i];
  __syncthreads();
  {
    const int g = lane >> 3, e = lane & 7;
    const float* gp = g2 + (size_t)g * D_M * E_N + e;
    float acc = 0.f;
    #pragma unroll 8
    for (int i = 0; i < D_M; i++) acc += xs[i] * gp[(size_t)i * E_N];
    l2s[g][e] = acc;
  }
  {
    const int g = lane >> 3, c = lane & 7;
    float acc = 0.f;
    #pragma unroll 8
    for (int i = c * 64; i < c * 64 + 64; i++) acc += xs[i] * g1[(size_t)i * G_N + g];
    l1part[g][c] = acc;
  }
  __syncthreads();
  if (lane < G_N) {
    float s = 0.f;
    #pragma unroll
    for (int c = 0; c < 8; c++) s += l1part[lane][c];
    l1s[lane] = s;
  }
  __syncthreads();
  if (lane == 0) {
    int a1 = 0;
    for (int g = 1; g < G_N; g++) if (l1s[g] > l1s[a1]) a1 = g;
    int a2 = (a1 == 0) ? 1 : 0;
    for (int g = 0; g < G_N; g++) if (g != a1 && l1s[g] > l1s[a2]) a2 = g;
    const float m = l1s[a1];
    float w1a = __expf(l1s[a1] - m), w1b = __expf(l1s[a2] - m);
    const float inv = 1.f / (w1a + w1b);
    w1a *= inv; w1b *= inv;
    const int gsel[2] = {a1, a2};
    const float wsel[2] = {w1a, w1b};
    for (int a = 0; a < 2; a++) {
      const int g = gsel[a];
      int e1 = 0;
      for (int e = 1; e < E_N; e++) if (l2s[g][e] > l2s[g][e1]) e1 = e;
      int e2 = (e1 == 0) ? 1 : 0;
      for (int e = 0; e < E_N; e++) if (e != e1 && l2s[g][e] > l2s[g][e2]) e2 = e;
      const float mm = l2s[g][e1];
      float ua = __expf(l2s[g][e1] - mm), ub = __expf(l2s[g][e2] - mm);
      const float uin = 1.f / (ua + ub);
      ua *= uin; ub *= uin;
      const int ge0 = g * E_N + e1;
      const int ge1 = g * E_N + e2;
      slotW[t * 4 + a * 2 + 0] = wsel[a] * ua;
      slotW[t * 4 + a * 2 + 1] = wsel[a] * ub;
      int p0 = atomicAdd(&counts[ge0], 1);
      list[ge0 * CAP + p0] = t * 4 + a * 2 + 0;
      int p1 = atomicAdd(&counts[ge1], 1);
      list[ge1 * CAP + p1] = t * 4 + a * 2 + 1;
    }
  }
}

// ---------------- GEMM1: h = relu(x @ W1 + b1) -> bf16. Barrier-free K-loop ----------------
// grid: 64 ge x 8 j-tiles(128) x 4 token-tiles. block 256 = 4 waves; wave owns 32 j (nt=2), 64 tokens (mt=4).
__global__ __launch_bounds__(256, 2) void k_mlp1(
    const float* __restrict__ x, const float* __restrict__ W1,
    const float* __restrict__ b1, const int* __restrict__ counts,
    const int* __restrict__ list, unsigned short* __restrict__ h_ws) {
  const int bx = blockIdx.x;
  const int ge = bx >> 5;
  const int j0 = ((bx >> 2) & 7) * 128;
  const int tt = bx & 3;
  const int n = counts[ge];
  if (tt * 64 >= n) return;
  __shared__ unsigned short xl[64 * LDK];   // [token][k] full-K, bf16
  __shared__ int tokTS[64];
  const int tid = threadIdx.x;
  const int lane = tid & 63, wave = tid >> 6;
  const int m16 = lane & 15, quad = lane >> 4;

  const float* Wcol = W1 + (size_t)ge * (D_M * H_M) + j0 + wave * 32 + m16;
  float bv[2];
  #pragma unroll
  for (int nt = 0; nt < 2; nt++) bv[nt] = b1[ge * H_M + j0 + wave * 32 + nt * 16 + m16];

  for (int t0 = tt * 64; t0 < n; t0 += 256) {
    __syncthreads();
    if (tid < 64) {
      int idx = t0 + tid;
      tokTS[tid] = list[ge * CAP + (idx < n ? idx : n - 1)];
    }
    __syncthreads();
    // stage x (fp32 -> bf16) once: thread covers token tid>>2, k-lane (tid&3)*4, 32 reps of 16 floats
    {
      const int trow = tid >> 2;
      const int kb = (tid & 3) * 4;
      const float* xr = x + (size_t)(tokTS[trow] >> 2) * D_M + kb;
      unsigned short* dst = &xl[trow * LDK + kb];
      #pragma unroll 8
      for (int rep = 0; rep < 32; rep++) {
        f32x4 v = *(const f32x4*)(xr + rep * 16);
        uint2 p = { pack2(v.x, v.y), pack2(v.z, v.w) };
        *(uint2*)(dst + rep * 16) = p;
      }
    }
    __syncthreads();

    f32x4 acc[4][2] = {};
    float bcur[2][8], bnxt[2][8];
    #pragma unroll
    for (int nt = 0; nt < 2; nt++)
      #pragma unroll
      for (int i = 0; i < 8; i++)
        bcur[nt][i] = Wcol[(size_t)(quad * 8 + i) * H_M + nt * 16];

    #pragma unroll 4
    for (int s = 0; s < 16; s++) {       // K = 512, no barriers
      if (s < 15) {
        #pragma unroll
        for (int nt = 0; nt < 2; nt++)
          #pragma unroll
          for (int i = 0; i < 8; i++)
            bnxt[nt][i] = Wcol[(size_t)((s + 1) * 32 + quad * 8 + i) * H_M + nt * 16];
      }
      bf16x8 bf[2];
      #pragma unroll
      for (int nt = 0; nt < 2; nt++) {
        u32x4 t = { pack2(bcur[nt][0], bcur[nt][1]), pack2(bcur[nt][2], bcur[nt][3]),
                    pack2(bcur[nt][4], bcur[nt][5]), pack2(bcur[nt][6], bcur[nt][7]) };
        bf[nt] = __builtin_bit_cast(bf16x8, t);
      }
      #pragma unroll
      for (int mt = 0; mt < 4; mt++) {
        bf16x8 af = *(bf16x8*)&xl[(mt * 16 + m16) * LDK + s * 32 + quad * 8];
        acc[mt][0] = __builtin_amdgcn_mfma_f32_16x16x32_bf16(af, bf[0], acc[mt][0], 0, 0, 0);
        acc[mt][1] = __builtin_amdgcn_mfma_f32_16x16x32_bf16(af, bf[1], acc[mt][1], 0, 0, 0);
      }
      #pragma unroll
      for (int nt = 0; nt < 2; nt++)
        #pragma unroll
        for (int i = 0; i < 8; i++) bcur[nt][i] = bnxt[nt][i];
    }
    // epilogue: bias + relu -> bf16
    #pragma unroll
    for (int mt = 0; mt < 4; mt++)
      #pragma unroll
      for (int i = 0; i < 4; i++) {
        const int tr = mt * 16 + quad * 4 + i;
        if (t0 + tr < n) {
          const int ts = tokTS[tr];
          unsigned short* hp = h_ws + (size_t)ts * H_M + j0 + wave * 32 + m16;
          #pragma unroll
          for (int nt = 0; nt < 2; nt++) {
            float v = acc[mt][nt][i] + bv[nt];
            hp[nt * 16] = f2bf(v > 0.f ? v : 0.f);
          }
        }
      }
  }
}

// ---------------- GEMM2: y_part = h @ W2 (+b2 on ks=0) -> fp32, K-split 2, barrier-free ----------------
// grid: 64 ge x 4 j-tiles(128) x 2 ksplit x 4 token-tiles.
__global__ __launch_bounds__(256, 2) void k_mlp2(
    const unsigned short* __restrict__ h_ws, const float* __restrict__ W2,
    const float* __restrict__ b2, const int* __restrict__ counts,
    const int* __restrict__ list, float* __restrict__ y0,
    float* __restrict__ y1) {
  const int bx = blockIdx.x;
  const int ge = bx >> 5;
  const int j0 = ((bx >> 3) & 3) * 128;
  const int ks = (bx >> 2) & 1;
  const int tt = bx & 3;
  const int n = counts[ge];
  if (tt * 64 >= n) return;
  __shared__ unsigned short xl[64 * LDK];   // [token][k-half], bf16
  __shared__ int tokTS[64];
  const int tid = threadIdx.x;
  const int lane = tid & 63, wave = tid >> 6;
  const int m16 = lane & 15, quad = lane >> 4;

  const float* Wcol = W2 + (size_t)ge * (H_M * D_M) + (size_t)(ks * 512) * D_M + j0 + wave * 32 + m16;
  float bv[2];
  #pragma unroll
  for (int nt = 0; nt < 2; nt++)
    bv[nt] = ks == 0 ? b2[ge * D_M + j0 + wave * 32 + nt * 16 + m16] : 0.f;
  float* yk = ks == 0 ? y0 : y1;

  for (int t0 = tt * 64; t0 < n; t0 += 256) {
    __syncthreads();
    if (tid < 64) {
      int idx = t0 + tid;
      tokTS[tid] = list[ge * CAP + (idx < n ? idx : n - 1)];
    }
    __syncthreads();
    // stage h-half (already bf16): thread covers token tid>>2, k-lane (tid&3)*8, 16 reps of 32 elems
    {
      const int trow = tid >> 2;
      const int kb = (tid & 3) * 8;
      const unsigned short* hr = h_ws + (size_t)tokTS[trow] * H_M + ks * 512 + kb;
      unsigned short* dst = &xl[trow * LDK + kb];
      #pragma unroll 8
      for (int rep = 0; rep < 16; rep++)
        *(u32x4*)(dst + rep * 32) = *(const u32x4*)(hr + rep * 32);
    }
    __syncthreads();

    f32x4 acc[4][2] = {};
    float bcur[2][8], bnxt[2][8];
    #pragma unroll
    for (int nt = 0; nt < 2; nt++)
      #pragma unroll
      for (int i = 0; i < 8; i++)
        bcur[nt][i] = Wcol[(size_t)(quad * 8 + i) * D_M + nt * 16];

    #pragma unroll 4
    for (int s = 0; s < 16; s++) {       // K-half = 512
      if (s < 15) {
        #pragma unroll
        for (int nt = 0; nt < 2; nt++)
          #pragma unroll
          for (int i = 0; i < 8; i++)
            bnxt[nt][i] = Wcol[(size_t)((s + 1) * 32 + quad * 8 + i) * D_M + nt * 16];
      }
      bf16x8 bf[2];
      #pragma unroll
      for (int nt = 0; nt < 2; nt++) {
        u32x4 t = { pack2(bcur[nt][0], bcur[nt][1]), pack2(bcur[nt][2], bcur[nt][3]),
                    pack2(bcur[nt][4], bcur[nt][5]), pack2(bcur[nt][6], bcur[nt][7]) };
        bf[nt] = __builtin_bit_cast(bf16x8, t);
      }
      #pragma unroll
      for (int mt = 0; mt < 4; mt++) {
        bf16x8 af = *(bf16x8*)&xl[(mt * 16 + m16) * LDK + s * 32 + quad * 8];
        acc[mt][0] = __builtin_amdgcn_mfma_f32_16x16x32_bf16(af, bf[0], acc[mt][0], 0, 0, 0);
        acc[mt][1] = __builtin_amdgcn_mfma_f32_16x16x32_bf16(af, bf[1], acc[mt][1], 0, 0, 0);
      }
      #pragma unroll
      for (int nt = 0; nt < 2; nt++)
        #pragma unroll
        for (int i = 0; i < 8; i++) bcur[nt][i] = bnxt[nt][i];
    }
    #pragma unroll
    for (int mt = 0; mt < 4; mt++)
      #pragma unroll
      for (int i = 0; i < 4; i++) {
        const int tr = mt * 16 + quad * 4 + i;
        if (t0 + tr < n) {
          const int ts = tokTS[tr];
          float* yp = yk + (size_t)ts * D_M + j0 + wave * 32 + m16;
          #pragma unroll
          for (int nt = 0; nt < 2; nt++)
            yp[nt * 16] = acc[mt][nt][i] + bv[nt];
        }
      }
  }
}

// ---------------- combine: out[t] = sum_s slotW[t,s] * (y0+y1)[t*4+s] ----------------
__global__ __launch_bounds__(256) void k_combine(
    const float* __restrict__ y0, const float* __restrict__ y1,
    const float* __restrict__ slotW, float* __restrict__ out) {
  const int idx = blockIdx.x * 256 + threadIdx.x;
  if (idx >= T_N * D_M / 4) return;
  const int t = idx >> 7;
  const int j = (idx & 127) * 4;
  float4 r = {0.f, 0.f, 0.f, 0.f};
  #pragma unroll
  for (int s = 0; s < 4; s++) {
    const float w = slotW[t * 4 + s];
    const size_t off = (size_t)(t * 4 + s) * D_M + j;
    const float4 a = *(const float4*)(y0 + off);
    const float4 b = *(const float4*)(y1 + off);
    r.x += w * (a.x + b.x);
    r.y += w * (a.y + b.y);
    r.z += w * (a.z + b.z);
    r.w += w * (a.w + b.w);
  }
  *(float4*)&out[(size_t)t * D_M + j] = r;
}

// ---------------- launch ----------------
extern "C" void kernel_launch(void* const* d_in, const int* in_sizes, int n_in,
                              void* d_out, int out_size, void* d_ws, size_t ws_size,
                              hipStream_t stream) {
  const float* x  = (const float*)d_in[0];
  const float* g1 = (const float*)d_in[1];
  const float* g2 = (const float*)d_in[2];
  const float* W1 = (const float*)d_in[3];
  const float* b1 = (const float*)d_in[4];
  const float* W2 = (const float*)d_in[5];
  const float* b2 = (const float*)d_in[6];
  float* out = (float*)d_out;

  char* ws = (char*)d_ws;
  float*          slotW  = (float*)(ws + 16384);               // 4096 floats
  int*            counts = (int*)(ws + 32768);                 // 64 ints
  int*            list   = (int*)(ws + 36864);                 // 64*1024 ints (256 KB)
  unsigned short* h_ws   = (unsigned short*)(ws + 524288);     // 4096*1024 bf16 (8 MB)
  float*          y0     = (float*)(ws + 524288 + 8388608);    // 4096*512 f32 (8 MB)
  float*          y1     = (float*)(ws + 524288 + 16777216);   // 4096*512 f32 (8 MB)

  hipMemsetAsync(counts, 0, NEXP * sizeof(int), stream);
  k_route<<<T_N, 64, 0, stream>>>(x, g1, g2, slotW, counts, list);
  k_mlp1<<<NEXP * 32, 256, 0, stream>>>(x, W1, b1, counts, list, h_ws);
  k_mlp2<<<NEXP * 32, 256, 0, stream>>>(h_ws, W2, b2, counts, list, y0, y1);
  k_combine<<<(T_N * D_M / 4) / 256, 256, 0, stream>>>(y0, y1, slotW, out);
}